// Round 17
// baseline (50.395 us; speedup 1.0000x reference)
//
#include <hip/hip_runtime.h>

// RmiModel: per-batch IMU preintegration.
// x: (B, 7, N) f32; ch0 = t (arange*0.01 -> dt const), ch1..6 raw imu.
// out: (B, 15) = [DR(3), DV(3), DC(9 row-major)].
//
// R16 = R15's packed FP32 + R7/R11's 32-lane geometry: 4 batches per wave.
//   Wave = 2 independent 32-lane groups; each group handles one packed
//   batch-pair (A in .x, B in .y of v2f). SEGL=8 (lane s owns steps
//   [8s,8s+8), lanes 25..31 idle -- validated R7/R11). The 5-round reduce
//   amortizes over 4 batches (~106 instr/batch vs R15's 255).
//   Registers: pair data = 24 float4 (96 VGPR) would trigger R13's
//   load-sinking, so split at j=4: burst0 (12 float4, 48 VGPR) -> scan
//   j=0..3 -> burst1 into the same window -> scan j=4..7. Both bursts
//   pinned (sched_barrier). Peak live ~115 VGPR: natural allocation,
//   NO launch_bounds min-waves (R12 spill lesson).
//   Carried validated pieces: SGPR calib (y = ch + bias + calib@ch, dt as
//   literals), Taylor so3_exp, lean ordered tree-reduce with analytic
//   partner duration, direct store, no LDS, no barriers. absmax 0.0039.

typedef float v2f __attribute__((ext_vector_type(2)));

constexpr int N     = 200;
constexpr int NSTEP = N - 1;      // 199
constexpr int TPB   = 256;        // 4 waves/block
constexpr int PPBLK = 8;          // pairs per block (4 waves x 2 groups)
constexpr float DT  = 0.01f;
constexpr float HDT = 0.5f * DT * DT;   // 5e-5

#define V2(a) ((v2f){(a), (a)})

__device__ __forceinline__ float f4e(const float4& v, int j) {
    return j == 0 ? v.x : j == 1 ? v.y : j == 2 ? v.z : v.w;
}

__device__ __forceinline__ int stepsBefore(int s) {   // steps in segments [0,s)
    int v = s << 3;
    return v > NSTEP ? NSTEP : v;
}

__global__ __launch_bounds__(TPB) void rmi_kernel(
    const float* __restrict__ x, const float* __restrict__ calib,
    const float* __restrict__ bias, float* __restrict__ out, int Bn)
{
    const int tid  = threadIdx.x;
    const int lane = tid & 63;
    const int wv   = tid >> 6;
    const int half = lane >> 5;   // group within wave
    const int s    = lane & 31;   // segment lane within group
    const int pair = blockIdx.x * PPBLK + wv * 2 + half;
    const int sA = 2 * pair, sB = 2 * pair + 1;   // store indices (guarded)
    int bA = sA, bB = sB;
    if (bA >= Bn) bA = Bn - 1;
    if (bB >= Bn) bB = Bn - 1;

    // lane s owns steps [8s, 8s+8); load window clamped for s >= 24
    const int off = (s < 24) ? (s << 3) : 192;
    const float* baseA = x + (size_t)bA * (7 * N) + N + off;
    const float* baseB = x + (size_t)bB * (7 * N) + N + off;

    // ---- calibration: uniform addresses -> s_load -> SGPRs (0 VGPR) ----
    float cal[36], bi6[6];
#pragma unroll
    for (int i = 0; i < 36; ++i) cal[i] = calib[i];
#pragma unroll
    for (int i = 0; i < 6; ++i) bi6[i] = bias[i];

    // packed per-lane segment state (A in .x, B in .y)
    v2f r0=V2(0.f), r1=V2(0.f), r2=V2(0.f);
    v2f v0=V2(0.f), v1=V2(0.f), v2=V2(0.f);
    v2f c00=V2(1.f), c01=V2(0.f), c02=V2(0.f);
    v2f c10=V2(0.f), c11=V2(1.f), c12=V2(0.f);
    v2f c20=V2(0.f), c21=V2(0.f), c22=V2(1.f);

    // one packed scan step: data from LA/LB element j, logical step n
    auto STEP = [&](const float4* LA, const float4* LB, int j, int n) {
        if (n < NSTEP) {
            v2f ch[6];
#pragma unroll
            for (int c = 0; c < 6; ++c)
                ch[c] = (v2f){ f4e(LA[c], j), f4e(LB[c], j) };
            // y = (I + calib) @ ch + bias (coeffs scalar-broadcast from SGPR)
            v2f y[6];
#pragma unroll
            for (int i = 0; i < 6; ++i) {
                v2f acc = ch[i] + bi6[i];
#pragma unroll
                for (int jj = 0; jj < 6; ++jj) acc += cal[i * 6 + jj] * ch[jj];
                y[i] = acc;
            }
            const v2f px = y[0] * DT, py = y[1] * DT, pz = y[2] * DT; // phi
            const v2f k0 = c00*y[3] + c01*y[4] + c02*y[5];            // C@a
            const v2f k1 = c10*y[3] + c11*y[4] + c12*y[5];
            const v2f k2 = c20*y[3] + c21*y[4] + c22*y[5];
            r0 += v0*DT + k0*HDT;
            r1 += v1*DT + k1*HDT;
            r2 += v2*DT + k2*HDT;
            v0 += k0*DT; v1 += k1*DT; v2 += k2*DT;
            // so3_exp(phi): Taylor in t2 (t2 <~ 1.5e-2; err ~ t2^3/5040)
            const v2f t2 = px*px + py*py + pz*pz;
            const v2f A  = 1.0f + t2*(-1.0f/6.0f  + t2*(1.0f/120.0f - t2*(1.0f/5040.0f)));
            const v2f Bc = 0.5f + t2*(-1.0f/24.0f + t2*(1.0f/720.0f - t2*(1.0f/40320.0f)));
            const v2f xx = px*px, yy = py*py, zz = pz*pz;
            const v2f xy = px*py, xz = px*pz, yz = py*pz;
            const v2f E00 = 1.0f - Bc*(yy+zz), E01 = Bc*xy - A*pz, E02 = Bc*xz + A*py;
            const v2f E10 = Bc*xy + A*pz, E11 = 1.0f - Bc*(xx+zz), E12 = Bc*yz - A*px;
            const v2f E20 = Bc*xz - A*py, E21 = Bc*yz + A*px, E22 = 1.0f - Bc*(xx+yy);
            const v2f n0 = c00*E00 + c01*E10 + c02*E20;
            const v2f n1 = c00*E01 + c01*E11 + c02*E21;
            const v2f n2 = c00*E02 + c01*E12 + c02*E22;
            const v2f n3 = c10*E00 + c11*E10 + c12*E20;
            const v2f n4 = c10*E01 + c11*E11 + c12*E21;
            const v2f n5 = c10*E02 + c11*E12 + c12*E22;
            const v2f n6 = c20*E00 + c21*E10 + c22*E20;
            const v2f n7 = c20*E01 + c21*E11 + c22*E21;
            const v2f n8 = c20*E02 + c21*E12 + c22*E22;
            c00=n0; c01=n1; c02=n2;
            c10=n3; c11=n4; c12=n5;
            c20=n6; c21=n7; c22=n8;
        }
    };

    // ---- burst0: steps off..off+3 of both batches (12 float4), pinned ----
    {
        float4 LA[6], LB[6];
#pragma unroll
        for (int c = 0; c < 6; ++c) {
            LA[c] = *reinterpret_cast<const float4*>(baseA + c * N);
            LB[c] = *reinterpret_cast<const float4*>(baseB + c * N);
        }
        __builtin_amdgcn_sched_barrier(0);
#pragma unroll
        for (int j = 0; j < 4; ++j) STEP(LA, LB, j, (s << 3) + j);
    }

    // ---- burst1: steps off+4..off+7 (burst0 dead), pinned ----
    {
        __builtin_amdgcn_sched_barrier(0);
        float4 LA[6], LB[6];
#pragma unroll
        for (int c = 0; c < 6; ++c) {
            LA[c] = *reinterpret_cast<const float4*>(baseA + c * N + 4);
            LB[c] = *reinterpret_cast<const float4*>(baseB + c * N + 4);
        }
        __builtin_amdgcn_sched_barrier(0);
#pragma unroll
        for (int j = 0; j < 4; ++j) STEP(LA, LB, j, (s << 3) + 4 + j);
    }

    // ---- lean ordered 5-round tree-reduce within each 32-lane group ----
    // After round r, lane s holds composite of segments [s, min(s+2^r,32)).
    // Clamped-src lanes self-compose (corrupted) but lane 0's dependency
    // tree (lanes 1,2,4,8,16 -- intact when read) never consumes them.
    // Idle lanes (s >= 25) hold identity, duration 0.
#pragma unroll
    for (int r = 0; r < 5; ++r) {
        const int d = 1 << r;
        const int src = (s + d < 32) ? (lane + d) : lane;
#define SH(v) ((v2f){ __shfl((v).x, src), __shfl((v).y, src) })
        const v2f oR0 = SH(r0), oR1 = SH(r1), oR2 = SH(r2);
        const v2f oV0 = SH(v0), oV1 = SH(v1), oV2 = SH(v2);
        const v2f o00 = SH(c00), o01 = SH(c01), o02 = SH(c02);
        const v2f o10 = SH(c10), o11 = SH(c11), o12 = SH(c12);
        const v2f o20 = SH(c20), o21 = SH(c21), o22 = SH(c22);
#undef SH
        // partner composite covers segments [s+d, s+2d) -> duration analytic
        const float bT = DT * (float)(stepsBefore(s + 2*d) - stepsBefore(s + d));
        r0 += v0*bT + c00*oR0 + c01*oR1 + c02*oR2;
        r1 += v1*bT + c10*oR0 + c11*oR1 + c12*oR2;
        r2 += v2*bT + c20*oR0 + c21*oR1 + c22*oR2;
        v0 += c00*oV0 + c01*oV1 + c02*oV2;
        v1 += c10*oV0 + c11*oV1 + c12*oV2;
        v2 += c20*oV0 + c21*oV1 + c22*oV2;
        const v2f m00 = c00*o00 + c01*o10 + c02*o20;
        const v2f m01 = c00*o01 + c01*o11 + c02*o21;
        const v2f m02 = c00*o02 + c01*o12 + c02*o22;
        const v2f m10 = c10*o00 + c11*o10 + c12*o20;
        const v2f m11 = c10*o01 + c11*o11 + c12*o21;
        const v2f m12 = c10*o02 + c11*o12 + c12*o22;
        const v2f m20 = c20*o00 + c21*o10 + c22*o20;
        const v2f m21 = c20*o01 + c21*o11 + c22*o21;
        const v2f m22 = c20*o02 + c21*o12 + c22*o22;
        c00=m00; c01=m01; c02=m02;
        c10=m10; c11=m11; c12=m12;
        c20=m20; c21=m21; c22=m22;
    }

    // ---- direct store: s==0 lane of each group writes both batches ----
    if (s == 0) {
        if (sA < Bn) {
            float* o = out + (size_t)sA * 15;
            o[0]=r0.x;  o[1]=r1.x;  o[2]=r2.x;
            o[3]=v0.x;  o[4]=v1.x;  o[5]=v2.x;
            o[6]=c00.x; o[7]=c01.x; o[8]=c02.x;
            o[9]=c10.x; o[10]=c11.x; o[11]=c12.x;
            o[12]=c20.x; o[13]=c21.x; o[14]=c22.x;
        }
        if (sB < Bn) {
            float* o = out + (size_t)sB * 15;
            o[0]=r0.y;  o[1]=r1.y;  o[2]=r2.y;
            o[3]=v0.y;  o[4]=v1.y;  o[5]=v2.y;
            o[6]=c00.y; o[7]=c01.y; o[8]=c02.y;
            o[9]=c10.y; o[10]=c11.y; o[11]=c12.y;
            o[12]=c20.y; o[13]=c21.y; o[14]=c22.y;
        }
    }
}

extern "C" void kernel_launch(void* const* d_in, const int* in_sizes, int n_in,
                              void* d_out, int out_size, void* d_ws, size_t ws_size,
                              hipStream_t stream) {
    const float* x     = (const float*)d_in[0];
    const float* calib = (const float*)d_in[1];
    const float* bias  = (const float*)d_in[2];
    float* out = (float*)d_out;
    const int Bn = in_sizes[0] / (7 * N);
    const int pairs = (Bn + 1) / 2;
    const int blocks = (pairs + PPBLK - 1) / PPBLK;
    rmi_kernel<<<blocks, TPB, 0, stream>>>(x, calib, bias, out, Bn);
}

// Round 18
// 44.104 us; speedup vs baseline: 1.1426x; 1.1426x over previous
//
#include <hip/hip_runtime.h>

// RmiModel: per-batch IMU preintegration.
// x: (B, 7, N) f32; ch0 = t (arange*0.01 -> dt const), ch1..6 raw imu.
// out: (B, 15) = [DR(3), DV(3), DC(9 row-major)].
//
// R17 = R15 (best, 45.5us) + DPP reduce.
//   R15's reduce issued 180 ds_bpermute/wave (30 packed values x 6 rounds).
//   Rounds d=1,2,4,8 stay within 16-lane DPP rows -> v_mov_b32_dpp row_shr:d
//   (1 VALU, no DS, no lgkm wait). Orientation flipped to the canonical
//   upward form (lane i reads i-d; result accumulates at lane 63, rocPRIM
//   pattern): partner = EARLIER segments = left compose operand. Rounds
//   d=16,32 cross rows -> __shfl (60 DS ops remain). Row-boundary lanes
//   keep own value (bound_ctrl=0) = self-compose corruption, provably
//   outside lane 63's dependency cone (all in-row cone reads have j-d>=0).
//   Self-duration analytic: bT = DT*(sb(s+1)-sb(s+1-d)), sb(k)=clamp(4k,0,199).
//   Carried from R15 (all validated, absmax 0.0039): packed v2f two batches
//   per lane (v_pk_*_f32), SEGL=4 (lane l owns steps [4l,4l+4), lanes>=50
//   idle/identity), single pinned 12x-float4 burst, SGPR calib
//   (y = ch + bias + calib@ch, dt literals), Taylor so3_exp, direct store
//   (lane 63), no LDS, no barriers.

typedef float v2f __attribute__((ext_vector_type(2)));

constexpr int N     = 200;
constexpr int NSTEP = N - 1;      // 199
constexpr int TPB   = 256;        // 4 waves/block, 1 pair/wave
constexpr int PPB   = 4;          // pairs per block
constexpr float DT  = 0.01f;
constexpr float HDT = 0.5f * DT * DT;   // 5e-5

#define V2(a) ((v2f){(a), (a)})

__device__ __forceinline__ float f4e(const float4& v, int j) {
    return j == 0 ? v.x : j == 1 ? v.y : j == 2 ? v.z : v.w;
}

__device__ __forceinline__ int sb(int s) {   // steps in segments [0,s), clamped
    int v = s < 0 ? 0 : (s << 2);
    return v > NSTEP ? NSTEP : v;
}

// DPP row_shr:d move (lane i <- lane i-d within 16-lane row; boundary lanes
// keep own value). CTRL = 0x110 + d.
template <int CTRL>
__device__ __forceinline__ v2f dpp_up(v2f v) {
    int xi = __float_as_int(v.x), yi = __float_as_int(v.y);
    int xr = __builtin_amdgcn_update_dpp(xi, xi, CTRL, 0xF, 0xF, false);
    int yr = __builtin_amdgcn_update_dpp(yi, yi, CTRL, 0xF, 0xF, false);
    return (v2f){ __int_as_float(xr), __int_as_float(yr) };
}

__global__ __launch_bounds__(TPB) void rmi_kernel(
    const float* __restrict__ x, const float* __restrict__ calib,
    const float* __restrict__ bias, float* __restrict__ out, int Bn)
{
    const int tid  = threadIdx.x;
    const int lane = tid & 63;
    const int wv   = tid >> 6;
    const int pair = blockIdx.x * PPB + wv;
    const int sA = 2 * pair, sB = 2 * pair + 1;   // store indices (guarded)
    int bA = sA, bB = sB;
    if (bA >= Bn) bA = Bn - 1;
    if (bB >= Bn) bB = Bn - 1;

    // lane owns steps [4*lane, 4*lane+4); load window clamped to 196
    const int off = (lane < 50) ? (lane << 2) : 196;
    const float* baseA = x + (size_t)bA * (7 * N) + N + off;
    const float* baseB = x + (size_t)bB * (7 * N) + N + off;

    // ---- single pinned burst: 6 float4 per batch (48 VGPR of data) ----
    float4 LA[6], LB[6];
#pragma unroll
    for (int c = 0; c < 6; ++c) {
        LA[c] = *reinterpret_cast<const float4*>(baseA + c * N);
        LB[c] = *reinterpret_cast<const float4*>(baseB + c * N);
    }
    __builtin_amdgcn_sched_barrier(0);   // do not sink

    // ---- calibration: uniform addresses -> s_load -> SGPRs (0 VGPR) ----
    float cal[36], bi6[6];
#pragma unroll
    for (int i = 0; i < 36; ++i) cal[i] = calib[i];
#pragma unroll
    for (int i = 0; i < 6; ++i) bi6[i] = bias[i];

    // packed per-lane segment state (A in .x, B in .y)
    v2f r0=V2(0.f), r1=V2(0.f), r2=V2(0.f);
    v2f v0=V2(0.f), v1=V2(0.f), v2=V2(0.f);
    v2f c00=V2(1.f), c01=V2(0.f), c02=V2(0.f);
    v2f c10=V2(0.f), c11=V2(1.f), c12=V2(0.f);
    v2f c20=V2(0.f), c21=V2(0.f), c22=V2(1.f);

#pragma unroll
    for (int j = 0; j < 4; ++j) {
        const int n = (lane << 2) + j;
        if (lane < 50 && n < NSTEP) {
            v2f ch[6];
#pragma unroll
            for (int c = 0; c < 6; ++c)
                ch[c] = (v2f){ f4e(LA[c], j), f4e(LB[c], j) };
            // y = (I + calib) @ ch + bias (coeffs scalar-broadcast from SGPR)
            v2f y[6];
#pragma unroll
            for (int i = 0; i < 6; ++i) {
                v2f acc = ch[i] + bi6[i];
#pragma unroll
                for (int jj = 0; jj < 6; ++jj) acc += cal[i * 6 + jj] * ch[jj];
                y[i] = acc;
            }
            const v2f px = y[0] * DT, py = y[1] * DT, pz = y[2] * DT; // phi
            const v2f k0 = c00*y[3] + c01*y[4] + c02*y[5];            // C@a
            const v2f k1 = c10*y[3] + c11*y[4] + c12*y[5];
            const v2f k2 = c20*y[3] + c21*y[4] + c22*y[5];
            r0 += v0*DT + k0*HDT;
            r1 += v1*DT + k1*HDT;
            r2 += v2*DT + k2*HDT;
            v0 += k0*DT; v1 += k1*DT; v2 += k2*DT;
            // so3_exp(phi): Taylor in t2 (t2 <~ 1.5e-2; err ~ t2^3/5040)
            const v2f t2 = px*px + py*py + pz*pz;
            const v2f A  = 1.0f + t2*(-1.0f/6.0f  + t2*(1.0f/120.0f - t2*(1.0f/5040.0f)));
            const v2f Bc = 0.5f + t2*(-1.0f/24.0f + t2*(1.0f/720.0f - t2*(1.0f/40320.0f)));
            const v2f xx = px*px, yy = py*py, zz = pz*pz;
            const v2f xy = px*py, xz = px*pz, yz = py*pz;
            const v2f E00 = 1.0f - Bc*(yy+zz), E01 = Bc*xy - A*pz, E02 = Bc*xz + A*py;
            const v2f E10 = Bc*xy + A*pz, E11 = 1.0f - Bc*(xx+zz), E12 = Bc*yz - A*px;
            const v2f E20 = Bc*xz - A*py, E21 = Bc*yz + A*px, E22 = 1.0f - Bc*(xx+yy);
            const v2f n0 = c00*E00 + c01*E10 + c02*E20;
            const v2f n1 = c00*E01 + c01*E11 + c02*E21;
            const v2f n2 = c00*E02 + c01*E12 + c02*E22;
            const v2f n3 = c10*E00 + c11*E10 + c12*E20;
            const v2f n4 = c10*E01 + c11*E11 + c12*E21;
            const v2f n5 = c10*E02 + c11*E12 + c12*E22;
            const v2f n6 = c20*E00 + c21*E10 + c22*E20;
            const v2f n7 = c20*E01 + c21*E11 + c22*E21;
            const v2f n8 = c20*E02 + c21*E12 + c22*E22;
            c00=n0; c01=n1; c02=n2;
            c10=n3; c11=n4; c12=n5;
            c20=n6; c21=n7; c22=n8;
        }
    }

    // ---- upward ordered tree-reduce (result at lane 63) ----
    // After round r, lane s holds composite of segments [s-2^(r+1)+1, s]
    // (clamped at 0). Received partner a (lane s-d) covers the EARLIER
    // segments -> a is the left compose operand:
    //   R = aR + aV*bT + aC@bR ; V = aV + aC@bV ; C = aC@bC
    // with b = self, bT = DT*(sb(s+1)-sb(s+1-d)) analytic.
    // Rounds d=1,2,4,8: DPP row_shr:d (in-row; boundary lanes self-compose,
    // provably outside lane 63's cone). Rounds d=16,32: __shfl.
#pragma unroll
    for (int r = 0; r < 6; ++r) {
        const int d = 1 << r;
        v2f oR0, oR1, oR2, oV0, oV1, oV2, o00, o01, o02, o10, o11, o12, o20, o21, o22;
        if (r < 4) {
#define DPPALL(CT)                                                          \
            oR0 = dpp_up<CT>(r0); oR1 = dpp_up<CT>(r1); oR2 = dpp_up<CT>(r2); \
            oV0 = dpp_up<CT>(v0); oV1 = dpp_up<CT>(v1); oV2 = dpp_up<CT>(v2); \
            o00 = dpp_up<CT>(c00); o01 = dpp_up<CT>(c01); o02 = dpp_up<CT>(c02); \
            o10 = dpp_up<CT>(c10); o11 = dpp_up<CT>(c11); o12 = dpp_up<CT>(c12); \
            o20 = dpp_up<CT>(c20); o21 = dpp_up<CT>(c21); o22 = dpp_up<CT>(c22);
            if (r == 0)      { DPPALL(0x111) }
            else if (r == 1) { DPPALL(0x112) }
            else if (r == 2) { DPPALL(0x114) }
            else             { DPPALL(0x118) }
#undef DPPALL
        } else {
            const int src = (lane >= d) ? (lane - d) : lane;
#define SH(v) ((v2f){ __shfl((v).x, src), __shfl((v).y, src) })
            oR0 = SH(r0); oR1 = SH(r1); oR2 = SH(r2);
            oV0 = SH(v0); oV1 = SH(v1); oV2 = SH(v2);
            o00 = SH(c00); o01 = SH(c01); o02 = SH(c02);
            o10 = SH(c10); o11 = SH(c11); o12 = SH(c12);
            o20 = SH(c20); o21 = SH(c21); o22 = SH(c22);
#undef SH
        }
        // self duration (b): segments [s+1-d, s]
        const float bT = DT * (float)(sb(lane + 1) - sb(lane + 1 - d));
        // new = compose(a=received, b=self)
        const v2f nR0 = oR0 + oV0*bT + o00*r0 + o01*r1 + o02*r2;
        const v2f nR1 = oR1 + oV1*bT + o10*r0 + o11*r1 + o12*r2;
        const v2f nR2 = oR2 + oV2*bT + o20*r0 + o21*r1 + o22*r2;
        const v2f nV0 = oV0 + o00*v0 + o01*v1 + o02*v2;
        const v2f nV1 = oV1 + o10*v0 + o11*v1 + o12*v2;
        const v2f nV2 = oV2 + o20*v0 + o21*v1 + o22*v2;
        const v2f m00 = o00*c00 + o01*c10 + o02*c20;
        const v2f m01 = o00*c01 + o01*c11 + o02*c21;
        const v2f m02 = o00*c02 + o01*c12 + o02*c22;
        const v2f m10 = o10*c00 + o11*c10 + o12*c20;
        const v2f m11 = o10*c01 + o11*c11 + o12*c21;
        const v2f m12 = o10*c02 + o11*c12 + o12*c22;
        const v2f m20 = o20*c00 + o21*c10 + o22*c20;
        const v2f m21 = o20*c01 + o21*c11 + o22*c21;
        const v2f m22 = o20*c02 + o21*c12 + o22*c22;
        r0=nR0; r1=nR1; r2=nR2;
        v0=nV0; v1=nV1; v2=nV2;
        c00=m00; c01=m01; c02=m02;
        c10=m10; c11=m11; c12=m12;
        c20=m20; c21=m21; c22=m22;
    }

    // ---- direct store: lane 63 holds [0,63] = full batch ----
    if (lane == 63) {
        if (sA < Bn) {
            float* o = out + (size_t)sA * 15;
            o[0]=r0.x;  o[1]=r1.x;  o[2]=r2.x;
            o[3]=v0.x;  o[4]=v1.x;  o[5]=v2.x;
            o[6]=c00.x; o[7]=c01.x; o[8]=c02.x;
            o[9]=c10.x; o[10]=c11.x; o[11]=c12.x;
            o[12]=c20.x; o[13]=c21.x; o[14]=c22.x;
        }
        if (sB < Bn) {
            float* o = out + (size_t)sB * 15;
            o[0]=r0.y;  o[1]=r1.y;  o[2]=r2.y;
            o[3]=v0.y;  o[4]=v1.y;  o[5]=v2.y;
            o[6]=c00.y; o[7]=c01.y; o[8]=c02.y;
            o[9]=c10.y; o[10]=c11.y; o[11]=c12.y;
            o[12]=c20.y; o[13]=c21.y; o[14]=c22.y;
        }
    }
}

extern "C" void kernel_launch(void* const* d_in, const int* in_sizes, int n_in,
                              void* d_out, int out_size, void* d_ws, size_t ws_size,
                              hipStream_t stream) {
    const float* x     = (const float*)d_in[0];
    const float* calib = (const float*)d_in[1];
    const float* bias  = (const float*)d_in[2];
    float* out = (float*)d_out;
    const int Bn = in_sizes[0] / (7 * N);
    const int pairs = (Bn + 1) / 2;
    const int blocks = (pairs + PPB - 1) / PPB;
    rmi_kernel<<<blocks, TPB, 0, stream>>>(x, calib, bias, out, Bn);
}